// Round 13
// baseline (256.104 us; speedup 1.0000x reference)
//
#include <hip/hip_runtime.h>
#include <hip/hip_bf16.h>
#include <math.h>

// ---------------------------------------------------------------------------
// GraphSAGE (gcn aggregator) x3 layers.
// R13: plane-split final aggregation (R9-verified math + R11-verified MLP).
//   R12 calibration: launch gaps ~1-2us; agg64 is ~40us hidden under the
//   top-5 cutoff with the same per-XCD L2-thrash as the fused aggs. Its cure
//   is proven: R9's %PL plane pinning (FETCH 81->29MB on PL=4) + 4-stream
//   unroll. g is emitted in 2-plane layout by fused<1> (R9 gemm23 epilogue
//   formula, verified). memset launch folded into cvt_all. Launches 8 -> 6.
//   Fused layer-1/2 aggs untouched: at compulsory-fetch floor (81MB ~= 8 XCD
//   x 11MB coupon-collector; 3 structures converged at ~51us).
// ---------------------------------------------------------------------------

#define NFEAT 128
#define BSH   7                 // bucket shift: 128 nodes per bucket
#define NBUKP 512               // padded bucket count (actual 391)
#define EPB2  1024              // edges per block in scatter pass
#define CAP   4000              // edge capacity per bucket (mean 2048, ~39 sigma)

typedef __attribute__((ext_vector_type(8))) short bf16x8;  // 8 bf16 = 4 VGPRs
typedef __attribute__((ext_vector_type(4))) float f32x4;

__device__ __forceinline__ unsigned short f2bf(float f) {  // RTNE fp32->bf16
    unsigned u = __float_as_uint(f);
    u += 0x7fffu + ((u >> 16) & 1u);
    return (unsigned short)(u >> 16);
}
__device__ __forceinline__ float bflo(unsigned u) { return __uint_as_float(u << 16); }
__device__ __forceinline__ float bfhi(unsigned u) { return __uint_as_float(u & 0xffff0000u); }

// ---- CSR pass 1: LDS-staged scatter into capacity-padded buckets ----------

__global__ __launch_bounds__(256) void build_scatter(const int* __restrict__ src,
                                                     const int* __restrict__ dst,
                                                     int* __restrict__ cursor,
                                                     unsigned long long* __restrict__ pairs,
                                                     int E) {
    __shared__ int hist[NBUKP];
    __shared__ int sc[NBUKP];
    __shared__ int lcur[NBUKP];
    __shared__ int lbase[NBUKP];
    __shared__ unsigned long long stage[EPB2];
    __shared__ int destIdx[EPB2];
    __shared__ int nLocalSh;

    const int t = threadIdx.x;
    hist[t] = 0; hist[t + 256] = 0;
    lcur[t] = 0; lcur[t + 256] = 0;
    __syncthreads();

    const int base = blockIdx.x * EPB2;
    int bb[EPB2 / 256];
    unsigned long long pr[EPB2 / 256];
#pragma unroll
    for (int j = 0; j < EPB2 / 256; ++j) {
        int e = base + t + 256 * j;
        bb[j] = -1;
        if (e < E) {
            int s = src[e], d = dst[e];
            int b = d >> BSH;
            bb[j] = b;
            pr[j] = ((unsigned long long)(unsigned)d << 32) | (unsigned)s;
            atomicAdd(&hist[b], 1);
        }
    }
    __syncthreads();
    sc[t] = hist[t]; sc[t + 256] = hist[t + 256];
    __syncthreads();
    for (int off = 1; off < NBUKP; off <<= 1) {
        int v0 = (t >= off) ? sc[t - off] : 0;
        int v1 = (t + 256 >= off) ? sc[t + 256 - off] : 0;
        __syncthreads();
        sc[t] += v0; sc[t + 256] += v1;
        __syncthreads();
    }
    if (t == 255) nLocalSh = sc[NBUKP - 1];
    sc[t] -= hist[t]; sc[t + 256] -= hist[t + 256];
    for (int b = t; b < NBUKP; b += 256) {
        int h = hist[b];
        if (h > 0) lbase[b] = atomicAdd(&cursor[b], h);
    }
    __syncthreads();
#pragma unroll
    for (int j = 0; j < EPB2 / 256; ++j) {
        int b = bb[j];
        if (b >= 0) {
            int slot = atomicAdd(&lcur[b], 1);
            int spos = sc[b] + slot;
            stage[spos] = pr[j];
            int rel = lbase[b] + slot;
            destIdx[spos] = (rel < CAP) ? (b * CAP + rel) : -1;
        }
    }
    __syncthreads();
    const int nLocal = nLocalSh;
#pragma unroll
    for (int j = 0; j < EPB2 / 256; ++j) {
        int i = t + 256 * j;
        if (i < nLocal && destIdx[i] >= 0) pairs[destIdx[i]] = stage[i];
    }
}

// ---- CSR pass 2: per-bucket sort by dst, emit row_beg/row_end/deg_inv -----

__global__ __launch_bounds__(256) void build_csr(const unsigned long long* __restrict__ pairs,
                                                 const int* __restrict__ cursor,
                                                 int* __restrict__ row_beg,
                                                 int* __restrict__ row_end,
                                                 float* __restrict__ deg_inv,
                                                 int* __restrict__ col_idx, int N) {
    __shared__ unsigned long long pairsL[CAP];
    __shared__ int srcS[CAP];
    __shared__ int nhist[128];
    __shared__ int npref[128];
    __shared__ int ncur[128];

    const int t = threadIdx.x;
    const int b = blockIdx.x;
    const int nodeBase = b << BSH;
    const int eBeg = b * CAP;
    int eCnt = cursor[b];
    if (eCnt > CAP) eCnt = CAP;

    if (t < 128) { nhist[t] = 0; ncur[t] = 0; }
    __syncthreads();

    for (int i = t; i < eCnt; i += 256) {
        unsigned long long p = pairs[eBeg + i];
        pairsL[i] = p;
        atomicAdd(&nhist[(int)(p >> 32) - nodeBase], 1);
    }
    __syncthreads();
    if (t < 128) npref[t] = nhist[t];
    __syncthreads();
    for (int off = 1; off < 128; off <<= 1) {
        int v = (t < 128 && t >= off) ? npref[t - off] : 0;
        __syncthreads();
        if (t < 128) npref[t] += v;
        __syncthreads();
    }
    if (t < 128) npref[t] -= nhist[t];
    if (t < 128 && nodeBase + t < N) {
        row_beg[nodeBase + t] = eBeg + npref[t];
        row_end[nodeBase + t] = eBeg + npref[t] + nhist[t];
        deg_inv[nodeBase + t] = 1.0f / (float)(nhist[t] + 1);
    }
    __syncthreads();
    for (int i = t; i < eCnt; i += 256) {
        unsigned long long p = pairsL[i];
        int d = (int)(p >> 32) - nodeBase;
        int slot = atomicAdd(&ncur[d], 1);
        srcS[npref[d] + slot] = (int)(unsigned)p;
    }
    __syncthreads();
    for (int i = t; i < eCnt; i += 256) col_idx[eBeg + i] = srcS[i];
}

// ---- merged fp32 -> bf16 convert (+ cursor zero): x, W1, W2, W3 -----------

__global__ __launch_bounds__(256) void cvt_all_kernel(const float* __restrict__ x,
                                                      const float* __restrict__ W1,
                                                      const float* __restrict__ W2,
                                                      const float* __restrict__ W3,
                                                      ushort* __restrict__ xb,
                                                      ushort* __restrict__ w1,
                                                      ushort* __restrict__ w2,
                                                      ushort* __restrict__ w3,
                                                      int* __restrict__ cursor, int nbuk,
                                                      int nx, int n1, int n2, int n3) {
    int i = blockIdx.x * blockDim.x + threadIdx.x;
    if (i < nbuk) cursor[i] = 0;
    const float* src; ushort* dst; int off;
    if (i < nx)                      { src = x;  dst = xb; off = i; }
    else if (i < nx + n1)            { src = W1; dst = w1; off = i - nx; }
    else if (i < nx + n1 + n2)       { src = W2; dst = w2; off = i - nx - n1; }
    else if (i < nx + n1 + n2 + n3)  { src = W3; dst = w3; off = i - nx - n1 - n2; }
    else return;
    float4 f = *(const float4*)(src + (size_t)off * 4);
    *(ushort4*)(dst + (size_t)off * 4) = make_ushort4(f2bf(f.x), f2bf(f.y), f2bf(f.z), f2bf(f.w));
}

// ---- Fused: 16-node agg -> LDS -> MFMA GEMM(s) ----------------------------
// Phase 1 = R11 wide-lane gather; phases 2/3 MFMA verified (m89/m91).
// SECOND: phase-3 writes g as 2 planes [2][N][32] (R9 gemm23 epilogue).

#define ACC8(u)                                                     \
    a0 += bflo((u).x); a1 += bfhi((u).x);                           \
    a2 += bflo((u).y); a3 += bfhi((u).y);                           \
    a4 += bflo((u).z); a5 += bfhi((u).z);                           \
    a6 += bflo((u).w); a7 += bfhi((u).w);

template<int SECOND>
__global__ __launch_bounds__(256) void fused_agg_gemm_kernel(
        const ushort* __restrict__ Xb,
        const int* __restrict__ row_beg,
        const int* __restrict__ row_end,
        const float* __restrict__ deg_inv,
        const ushort* __restrict__ Wb,     // [128,128] bf16
        const float* __restrict__ bias,    // [128]
        const ushort* __restrict__ W3b,    // [64,128] bf16 (SECOND only)
        const int* __restrict__ col_idx,
        ushort* __restrict__ outB, int N) {
    __shared__ ushort A[16][136];
    __shared__ ushort H2[SECOND ? 16 : 1][136];

    const int t    = threadIdx.x;
    const int w    = t >> 6;
    const int lane = t & 63;
    const int g    = lane >> 4;
    const int f    = lane & 15;
    const int base = blockIdx.x * 16;
    const uint4* X4 = (const uint4*)Xb;              // row stride 16 uint4

    // ---- phase 1: aggregate 4 nodes per wave into LDS ----
#pragma unroll
    for (int i = 0; i < 4; ++i) {
        const int v = base + w * 4 + i;
        if (v < N) {
            const int beg = row_beg[v];
            const int end = row_end[v];

            float a0 = 0.f, a1 = 0.f, a2 = 0.f, a3 = 0.f;
            float a4 = 0.f, a5 = 0.f, a6 = 0.f, a7 = 0.f;
            int e = beg + g;
            for (; e + 12 < end; e += 16) {
                int s0 = col_idx[e];
                int s1 = col_idx[e + 4];
                int s2 = col_idx[e + 8];
                int s3 = col_idx[e + 12];
                uint4 u0 = X4[(size_t)s0 * 16 + f];
                uint4 u1 = X4[(size_t)s1 * 16 + f];
                uint4 u2 = X4[(size_t)s2 * 16 + f];
                uint4 u3 = X4[(size_t)s3 * 16 + f];
                ACC8(u0); ACC8(u1); ACC8(u2); ACC8(u3);
            }
            for (; e < end; e += 4) {
                uint4 u = X4[(size_t)col_idx[e] * 16 + f];
                ACC8(u);
            }
            a0 += __shfl_xor(a0, 16, 64); a0 += __shfl_xor(a0, 32, 64);
            a1 += __shfl_xor(a1, 16, 64); a1 += __shfl_xor(a1, 32, 64);
            a2 += __shfl_xor(a2, 16, 64); a2 += __shfl_xor(a2, 32, 64);
            a3 += __shfl_xor(a3, 16, 64); a3 += __shfl_xor(a3, 32, 64);
            a4 += __shfl_xor(a4, 16, 64); a4 += __shfl_xor(a4, 32, 64);
            a5 += __shfl_xor(a5, 16, 64); a5 += __shfl_xor(a5, 32, 64);
            a6 += __shfl_xor(a6, 16, 64); a6 += __shfl_xor(a6, 32, 64);
            a7 += __shfl_xor(a7, 16, 64); a7 += __shfl_xor(a7, 32, 64);
            if (g == 0) {
                uint4 us = X4[(size_t)v * 16 + f];
                float inv = deg_inv[v];
                uint4 r;
                r.x = (unsigned)f2bf((a0 + bflo(us.x)) * inv) | ((unsigned)f2bf((a1 + bfhi(us.x)) * inv) << 16);
                r.y = (unsigned)f2bf((a2 + bflo(us.y)) * inv) | ((unsigned)f2bf((a3 + bfhi(us.y)) * inv) << 16);
                r.z = (unsigned)f2bf((a4 + bflo(us.z)) * inv) | ((unsigned)f2bf((a5 + bfhi(us.z)) * inv) << 16);
                r.w = (unsigned)f2bf((a6 + bflo(us.w)) * inv) | ((unsigned)f2bf((a7 + bfhi(us.w)) * inv) << 16);
                ((uint4*)&A[w * 4 + i][0])[f] = r;
            }
        }
    }
    __syncthreads();

    // ---- phase 2: relu(A @ W^T + b), wave w -> cols [32w, 32w+32) ----
    const int m    = lane & 15;
    const int quad = lane >> 4;
    f32x4 acc0 = {0.f, 0.f, 0.f, 0.f};
    f32x4 acc1 = {0.f, 0.f, 0.f, 0.f};
    {
        const ushort* arow = &A[m][quad * 8];
        const ushort* wrow = Wb + (size_t)(w * 32 + m) * NFEAT + quad * 8;
#pragma unroll
        for (int k0 = 0; k0 < NFEAT; k0 += 32) {
            bf16x8 a  = *(const bf16x8*)(arow + k0);
            bf16x8 bA = *(const bf16x8*)(wrow + k0);
            bf16x8 bB = *(const bf16x8*)(wrow + 16 * NFEAT + k0);
            acc0 = __builtin_amdgcn_mfma_f32_16x16x32_bf16(a, bA, acc0, 0, 0, 0);
            acc1 = __builtin_amdgcn_mfma_f32_16x16x32_bf16(a, bB, acc1, 0, 0, 0);
        }
    }
    const float bv0 = bias[w * 32 + m];
    const float bv1 = bias[w * 32 + 16 + m];

    if (!SECOND) {
#pragma unroll
        for (int r = 0; r < 4; ++r) {
            int row = base + quad * 4 + r;
            if (row < N) {
                outB[(size_t)row * NFEAT + w * 32 + m]      = f2bf(fmaxf(acc0[r] + bv0, 0.f));
                outB[(size_t)row * NFEAT + w * 32 + 16 + m] = f2bf(fmaxf(acc1[r] + bv1, 0.f));
            }
        }
    } else {
#pragma unroll
        for (int r = 0; r < 4; ++r) {
            H2[quad * 4 + r][w * 32 + m]      = f2bf(fmaxf(acc0[r] + bv0, 0.f));
            H2[quad * 4 + r][w * 32 + 16 + m] = f2bf(fmaxf(acc1[r] + bv1, 0.f));
        }
        __syncthreads();
        // ---- phase 3: G = H2 @ W3^T, wave w -> cols [16w, 16w+16) ----
        // epilogue writes plane layout [2][N][32] (R9-verified formula)
        f32x4 acc3 = {0.f, 0.f, 0.f, 0.f};
        const ushort* hrow  = &H2[m][quad * 8];
        const ushort* w3row = W3b + (size_t)(w * 16 + m) * NFEAT + quad * 8;
#pragma unroll
        for (int k0 = 0; k0 < NFEAT; k0 += 32) {
            bf16x8 a = *(const bf16x8*)(hrow + k0);
            bf16x8 b = *(const bf16x8*)(w3row + k0);
            acc3 = __builtin_amdgcn_mfma_f32_16x16x32_bf16(a, b, acc3, 0, 0, 0);
        }
#pragma unroll
        for (int r = 0; r < 4; ++r) {
            int row = base + quad * 4 + r;
            if (row < N)
                outB[((size_t)(w >> 1) * N + row) * 32 + (w & 1) * 16 + m] = f2bf(acc3[r]);
        }
    }
}

// ---- Final aggregation: plane-split (PL=2) + bias + sigmoid ---------------
// g stored as 2 planes [2][N][32 feats] (3.2 MB each). plane = blockIdx % 2
// (XCD-pinned via %8 round-robin dispatch). Gather: R9-verified direct
// col_idx pattern, 4-stream unroll (R11-verified loop shape); shfl_xor
// butterfly over 4 edge groups; bias/sigmoid formula R9-verified.

__global__ __launch_bounds__(256) void agg64_plane_kernel(
        const ushort* __restrict__ Gpl,
        const int* __restrict__ row_beg,
        const int* __restrict__ row_end,
        const float* __restrict__ deg_inv,
        const int* __restrict__ col_idx,
        const float* __restrict__ bias,
        float* __restrict__ out, int N) {
    const int s    = blockIdx.x & 1;
    const int tile = blockIdx.x >> 1;
    const int w    = threadIdx.x >> 6;
    const int lane = threadIdx.x & 63;
    const int g    = lane >> 4;
    const int f    = lane & 15;
    const unsigned* P = (const unsigned*)Gpl + (size_t)s * N * 16;

#pragma unroll
    for (int i = 0; i < 4; ++i) {
        const int v = tile * 16 + w * 4 + i;
        if (v >= N) continue;
        const int beg = row_beg[v];
        const int end = row_end[v];

        float a0 = 0.f, a1 = 0.f, b0 = 0.f, b1 = 0.f;
        float c0 = 0.f, c1 = 0.f, d0 = 0.f, d1 = 0.f;
        int e = beg + g;
        for (; e + 12 < end; e += 16) {
            int s0 = col_idx[e];
            int s1 = col_idx[e + 4];
            int s2 = col_idx[e + 8];
            int s3 = col_idx[e + 12];
            unsigned u0 = P[(size_t)s0 * 16 + f];
            unsigned u1 = P[(size_t)s1 * 16 + f];
            unsigned u2 = P[(size_t)s2 * 16 + f];
            unsigned u3 = P[(size_t)s3 * 16 + f];
            a0 += bflo(u0); a1 += bfhi(u0);
            b0 += bflo(u1); b1 += bfhi(u1);
            c0 += bflo(u2); c1 += bfhi(u2);
            d0 += bflo(u3); d1 += bfhi(u3);
        }
        for (; e < end; e += 4) {
            unsigned u0 = P[(size_t)col_idx[e] * 16 + f];
            a0 += bflo(u0); a1 += bfhi(u0);
        }
        a0 += b0 + c0 + d0;
        a1 += b1 + c1 + d1;
        a0 += __shfl_xor(a0, 16, 64); a0 += __shfl_xor(a0, 32, 64);
        a1 += __shfl_xor(a1, 16, 64); a1 += __shfl_xor(a1, 32, 64);
        if (g == 0) {
            unsigned us = P[(size_t)v * 16 + f];
            float inv = deg_inv[v];
            float r0 = (a0 + bflo(us)) * inv + bias[s * 32 + 2 * f + 0];
            float r1 = (a1 + bfhi(us)) * inv + bias[s * 32 + 2 * f + 1];
            r0 = 1.0f / (1.0f + __expf(-r0));
            r1 = 1.0f / (1.0f + __expf(-r1));
            *(float2*)(out + (size_t)v * 64 + s * 32 + 2 * f) = make_float2(r0, r1);
        }
    }
}

// ---------------------------------------------------------------------------

static inline size_t align256(size_t x) { return (x + 255) & ~(size_t)255; }

extern "C" void kernel_launch(void* const* d_in, const int* in_sizes, int n_in,
                              void* d_out, int out_size, void* d_ws, size_t ws_size,
                              hipStream_t stream) {
    const float* x   = (const float*)d_in[0];
    const int*   src = (const int*)d_in[1];
    const int*   dst = (const int*)d_in[2];
    const float* W1  = (const float*)d_in[3];
    const float* b1  = (const float*)d_in[4];
    const float* W2  = (const float*)d_in[5];
    const float* b2  = (const float*)d_in[6];
    const float* W3  = (const float*)d_in[7];
    const float* b3  = (const float*)d_in[8];
    float*       out = (float*)d_out;

    const int N = in_sizes[0] / NFEAT;     // 50000
    const int E = in_sizes[1];             // 800000
    const int D_OUT = in_sizes[7] / NFEAT; // 64
    const int NBUK = (N + (1 << BSH) - 1) >> BSH;   // 391
    const int SBLK = (E + EPB2 - 1) / EPB2;         // 782

    // workspace carve:
    char* ws = (char*)d_ws;
    int* row_beg      = (int*)ws;  ws += align256((size_t)N * 4);
    int* row_end      = (int*)ws;  ws += align256((size_t)N * 4);
    float* deg_inv    = (float*)ws; ws += align256((size_t)N * 4);
    int* cursor       = (int*)ws;  ws += align256((size_t)NBUK * 4);
    int* col_idx      = (int*)ws;  ws += align256((size_t)NBUK * CAP * 4);
    ushort* w1bf      = (ushort*)ws; ws += align256((size_t)NFEAT * NFEAT * 2);
    ushort* w2bf      = (ushort*)ws; ws += align256((size_t)NFEAT * NFEAT * 2);
    ushort* w3bf      = (ushort*)ws; ws += align256((size_t)D_OUT * NFEAT * 2);
    ushort* xbf       = (ushort*)ws; ws += align256((size_t)N * NFEAT * 2);
    ushort* h1bf      = (ushort*)ws; ws += align256((size_t)N * NFEAT * 2);
    ushort* gpl = xbf;                                      // x dead after fused<0>; [2][N][32]
    unsigned long long* pairs = (unsigned long long*)h1bf;  // 12.5MB <= 12.8MB, dead before fused<0>

    // ---- convert (also zeroes cursor) ----
    const int nx = N * NFEAT / 4;
    const int n1 = NFEAT * NFEAT / 4, n2 = NFEAT * NFEAT / 4, n3 = D_OUT * NFEAT / 4;
    cvt_all_kernel<<<(nx + n1 + n2 + n3 + 255) / 256, 256, 0, stream>>>(
        x, W1, W2, W3, xbf, w1bf, w2bf, w3bf, cursor, NBUK, nx, n1, n2, n3);

    // ---- CSR build: 2 passes ----
    build_scatter<<<SBLK, 256, 0, stream>>>(src, dst, cursor, pairs, E);
    build_csr<<<NBUK, 256, 0, stream>>>(pairs, cursor, row_beg, row_end, deg_inv, col_idx, N);

    const int fusedBlocks = (N + 15) / 16;   // 3125
    const int tiles       = (N + 15) / 16;

    // layer 1: agg(x) -> MFMA W1 + b1 + relu -> h1bf
    fused_agg_gemm_kernel<0><<<fusedBlocks, 256, 0, stream>>>(
        xbf, row_beg, row_end, deg_inv, w1bf, b1, nullptr, col_idx, h1bf, N);
    // layers 2+3a: agg(h1) -> MFMA W2 + b2 + relu -> MFMA W3 -> g planes
    fused_agg_gemm_kernel<1><<<fusedBlocks, 256, 0, stream>>>(
        h1bf, row_beg, row_end, deg_inv, w2bf, b2, w3bf, col_idx, gpl, N);
    // layer 3b: plane-split aggregate g + b3 + sigmoid -> out
    agg64_plane_kernel<<<tiles * 2, 256, 0, stream>>>(
        gpl, row_beg, row_end, deg_inv, col_idx, b3, out, N);
}

// Round 14
// 234.006 us; speedup vs baseline: 1.0944x; 1.0944x over previous
//
#include <hip/hip_runtime.h>
#include <hip/hip_bf16.h>
#include <math.h>

// ---------------------------------------------------------------------------
// GraphSAGE (gcn aggregator) x3 layers.
// R14 = R12 revert (best: 237.8us) + R13's orthogonal cursor-fold (no memset).
//   R13 post-mortem: plane-split agg64 regressed +18us (2x per-edge overhead
//   > locality win; matches R9's PL=4 result — branch closed).
//   Structure: cvt_all (zeroes cursor) -> build_scatter -> build_csr ->
//   fused<0> (agg+W1+relu) -> fused<1> (agg+W2+relu+W3) -> agg64_sigmoid.
//   Fused aggs at compulsory-fetch floor: 81MB ~= 8 XCD x 11MB coupon-
//   collector over the 12.8MB bf16 operand; 3 gather structures + MLP/
//   locality probes all converge at ~51us.
// ---------------------------------------------------------------------------

#define NFEAT 128
#define BSH   7                 // bucket shift: 128 nodes per bucket
#define NBUKP 512               // padded bucket count (actual 391)
#define EPB2  1024              // edges per block in scatter pass
#define CAP   4000              // edge capacity per bucket (mean 2048, ~39 sigma)

typedef __attribute__((ext_vector_type(8))) short bf16x8;  // 8 bf16 = 4 VGPRs
typedef __attribute__((ext_vector_type(4))) float f32x4;

__device__ __forceinline__ unsigned short f2bf(float f) {  // RTNE fp32->bf16
    unsigned u = __float_as_uint(f);
    u += 0x7fffu + ((u >> 16) & 1u);
    return (unsigned short)(u >> 16);
}
__device__ __forceinline__ float bflo(unsigned u) { return __uint_as_float(u << 16); }
__device__ __forceinline__ float bfhi(unsigned u) { return __uint_as_float(u & 0xffff0000u); }

// ---- CSR pass 1: LDS-staged scatter into capacity-padded buckets ----------

__global__ __launch_bounds__(256) void build_scatter(const int* __restrict__ src,
                                                     const int* __restrict__ dst,
                                                     int* __restrict__ cursor,
                                                     unsigned long long* __restrict__ pairs,
                                                     int E) {
    __shared__ int hist[NBUKP];
    __shared__ int sc[NBUKP];
    __shared__ int lcur[NBUKP];
    __shared__ int lbase[NBUKP];
    __shared__ unsigned long long stage[EPB2];
    __shared__ int destIdx[EPB2];
    __shared__ int nLocalSh;

    const int t = threadIdx.x;
    hist[t] = 0; hist[t + 256] = 0;
    lcur[t] = 0; lcur[t + 256] = 0;
    __syncthreads();

    const int base = blockIdx.x * EPB2;
    int bb[EPB2 / 256];
    unsigned long long pr[EPB2 / 256];
#pragma unroll
    for (int j = 0; j < EPB2 / 256; ++j) {
        int e = base + t + 256 * j;
        bb[j] = -1;
        if (e < E) {
            int s = src[e], d = dst[e];
            int b = d >> BSH;
            bb[j] = b;
            pr[j] = ((unsigned long long)(unsigned)d << 32) | (unsigned)s;
            atomicAdd(&hist[b], 1);
        }
    }
    __syncthreads();
    sc[t] = hist[t]; sc[t + 256] = hist[t + 256];
    __syncthreads();
    for (int off = 1; off < NBUKP; off <<= 1) {
        int v0 = (t >= off) ? sc[t - off] : 0;
        int v1 = (t + 256 >= off) ? sc[t + 256 - off] : 0;
        __syncthreads();
        sc[t] += v0; sc[t + 256] += v1;
        __syncthreads();
    }
    if (t == 255) nLocalSh = sc[NBUKP - 1];
    sc[t] -= hist[t]; sc[t + 256] -= hist[t + 256];
    for (int b = t; b < NBUKP; b += 256) {
        int h = hist[b];
        if (h > 0) lbase[b] = atomicAdd(&cursor[b], h);
    }
    __syncthreads();
#pragma unroll
    for (int j = 0; j < EPB2 / 256; ++j) {
        int b = bb[j];
        if (b >= 0) {
            int slot = atomicAdd(&lcur[b], 1);
            int spos = sc[b] + slot;
            stage[spos] = pr[j];
            int rel = lbase[b] + slot;
            destIdx[spos] = (rel < CAP) ? (b * CAP + rel) : -1;
        }
    }
    __syncthreads();
    const int nLocal = nLocalSh;
#pragma unroll
    for (int j = 0; j < EPB2 / 256; ++j) {
        int i = t + 256 * j;
        if (i < nLocal && destIdx[i] >= 0) pairs[destIdx[i]] = stage[i];
    }
}

// ---- CSR pass 2: per-bucket sort by dst, emit row_beg/row_end/deg_inv -----

__global__ __launch_bounds__(256) void build_csr(const unsigned long long* __restrict__ pairs,
                                                 const int* __restrict__ cursor,
                                                 int* __restrict__ row_beg,
                                                 int* __restrict__ row_end,
                                                 float* __restrict__ deg_inv,
                                                 int* __restrict__ col_idx, int N) {
    __shared__ unsigned long long pairsL[CAP];
    __shared__ int srcS[CAP];
    __shared__ int nhist[128];
    __shared__ int npref[128];
    __shared__ int ncur[128];

    const int t = threadIdx.x;
    const int b = blockIdx.x;
    const int nodeBase = b << BSH;
    const int eBeg = b * CAP;
    int eCnt = cursor[b];
    if (eCnt > CAP) eCnt = CAP;

    if (t < 128) { nhist[t] = 0; ncur[t] = 0; }
    __syncthreads();

    for (int i = t; i < eCnt; i += 256) {
        unsigned long long p = pairs[eBeg + i];
        pairsL[i] = p;
        atomicAdd(&nhist[(int)(p >> 32) - nodeBase], 1);
    }
    __syncthreads();
    if (t < 128) npref[t] = nhist[t];
    __syncthreads();
    for (int off = 1; off < 128; off <<= 1) {
        int v = (t < 128 && t >= off) ? npref[t - off] : 0;
        __syncthreads();
        if (t < 128) npref[t] += v;
        __syncthreads();
    }
    if (t < 128) npref[t] -= nhist[t];
    if (t < 128 && nodeBase + t < N) {
        row_beg[nodeBase + t] = eBeg + npref[t];
        row_end[nodeBase + t] = eBeg + npref[t] + nhist[t];
        deg_inv[nodeBase + t] = 1.0f / (float)(nhist[t] + 1);
    }
    __syncthreads();
    for (int i = t; i < eCnt; i += 256) {
        unsigned long long p = pairsL[i];
        int d = (int)(p >> 32) - nodeBase;
        int slot = atomicAdd(&ncur[d], 1);
        srcS[npref[d] + slot] = (int)(unsigned)p;
    }
    __syncthreads();
    for (int i = t; i < eCnt; i += 256) col_idx[eBeg + i] = srcS[i];
}

// ---- merged fp32 -> bf16 convert (+ cursor zero): x, W1, W2, W3 -----------

__global__ __launch_bounds__(256) void cvt_all_kernel(const float* __restrict__ x,
                                                      const float* __restrict__ W1,
                                                      const float* __restrict__ W2,
                                                      const float* __restrict__ W3,
                                                      ushort* __restrict__ xb,
                                                      ushort* __restrict__ w1,
                                                      ushort* __restrict__ w2,
                                                      ushort* __restrict__ w3,
                                                      int* __restrict__ cursor, int nbuk,
                                                      int nx, int n1, int n2, int n3) {
    int i = blockIdx.x * blockDim.x + threadIdx.x;
    if (i < nbuk) cursor[i] = 0;
    const float* src; ushort* dst; int off;
    if (i < nx)                      { src = x;  dst = xb; off = i; }
    else if (i < nx + n1)            { src = W1; dst = w1; off = i - nx; }
    else if (i < nx + n1 + n2)       { src = W2; dst = w2; off = i - nx - n1; }
    else if (i < nx + n1 + n2 + n3)  { src = W3; dst = w3; off = i - nx - n1 - n2; }
    else return;
    float4 f = *(const float4*)(src + (size_t)off * 4);
    *(ushort4*)(dst + (size_t)off * 4) = make_ushort4(f2bf(f.x), f2bf(f.y), f2bf(f.z), f2bf(f.w));
}

// ---- Fused: 16-node agg -> LDS -> MFMA GEMM(s) ----------------------------
// Phase 1: R11 wide-lane gather (16 lanes x uint4/edge, 4 edge groups,
// 4-stream unroll, shfl_xor butterfly). Phases 2/3 MFMA (layout m89/m91).

#define ACC8(u)                                                     \
    a0 += bflo((u).x); a1 += bfhi((u).x);                           \
    a2 += bflo((u).y); a3 += bfhi((u).y);                           \
    a4 += bflo((u).z); a5 += bfhi((u).z);                           \
    a6 += bflo((u).w); a7 += bfhi((u).w);

template<int SECOND>
__global__ __launch_bounds__(256) void fused_agg_gemm_kernel(
        const ushort* __restrict__ Xb,
        const int* __restrict__ row_beg,
        const int* __restrict__ row_end,
        const float* __restrict__ deg_inv,
        const ushort* __restrict__ Wb,     // [128,128] bf16
        const float* __restrict__ bias,    // [128]
        const ushort* __restrict__ W3b,    // [64,128] bf16 (SECOND only)
        const int* __restrict__ col_idx,
        ushort* __restrict__ outB, int N) {
    __shared__ ushort A[16][136];
    __shared__ ushort H2[SECOND ? 16 : 1][136];

    const int t    = threadIdx.x;
    const int w    = t >> 6;
    const int lane = t & 63;
    const int g    = lane >> 4;
    const int f    = lane & 15;
    const int base = blockIdx.x * 16;
    const uint4* X4 = (const uint4*)Xb;              // row stride 16 uint4

    // ---- phase 1: aggregate 4 nodes per wave into LDS ----
#pragma unroll
    for (int i = 0; i < 4; ++i) {
        const int v = base + w * 4 + i;
        if (v < N) {
            const int beg = row_beg[v];
            const int end = row_end[v];

            float a0 = 0.f, a1 = 0.f, a2 = 0.f, a3 = 0.f;
            float a4 = 0.f, a5 = 0.f, a6 = 0.f, a7 = 0.f;
            int e = beg + g;
            for (; e + 12 < end; e += 16) {
                int s0 = col_idx[e];
                int s1 = col_idx[e + 4];
                int s2 = col_idx[e + 8];
                int s3 = col_idx[e + 12];
                uint4 u0 = X4[(size_t)s0 * 16 + f];
                uint4 u1 = X4[(size_t)s1 * 16 + f];
                uint4 u2 = X4[(size_t)s2 * 16 + f];
                uint4 u3 = X4[(size_t)s3 * 16 + f];
                ACC8(u0); ACC8(u1); ACC8(u2); ACC8(u3);
            }
            for (; e < end; e += 4) {
                uint4 u = X4[(size_t)col_idx[e] * 16 + f];
                ACC8(u);
            }
            a0 += __shfl_xor(a0, 16, 64); a0 += __shfl_xor(a0, 32, 64);
            a1 += __shfl_xor(a1, 16, 64); a1 += __shfl_xor(a1, 32, 64);
            a2 += __shfl_xor(a2, 16, 64); a2 += __shfl_xor(a2, 32, 64);
            a3 += __shfl_xor(a3, 16, 64); a3 += __shfl_xor(a3, 32, 64);
            a4 += __shfl_xor(a4, 16, 64); a4 += __shfl_xor(a4, 32, 64);
            a5 += __shfl_xor(a5, 16, 64); a5 += __shfl_xor(a5, 32, 64);
            a6 += __shfl_xor(a6, 16, 64); a6 += __shfl_xor(a6, 32, 64);
            a7 += __shfl_xor(a7, 16, 64); a7 += __shfl_xor(a7, 32, 64);
            if (g == 0) {
                uint4 us = X4[(size_t)v * 16 + f];
                float inv = deg_inv[v];
                uint4 r;
                r.x = (unsigned)f2bf((a0 + bflo(us.x)) * inv) | ((unsigned)f2bf((a1 + bfhi(us.x)) * inv) << 16);
                r.y = (unsigned)f2bf((a2 + bflo(us.y)) * inv) | ((unsigned)f2bf((a3 + bfhi(us.y)) * inv) << 16);
                r.z = (unsigned)f2bf((a4 + bflo(us.z)) * inv) | ((unsigned)f2bf((a5 + bfhi(us.z)) * inv) << 16);
                r.w = (unsigned)f2bf((a6 + bflo(us.w)) * inv) | ((unsigned)f2bf((a7 + bfhi(us.w)) * inv) << 16);
                ((uint4*)&A[w * 4 + i][0])[f] = r;
            }
        }
    }
    __syncthreads();

    // ---- phase 2: relu(A @ W^T + b), wave w -> cols [32w, 32w+32) ----
    const int m    = lane & 15;
    const int quad = lane >> 4;
    f32x4 acc0 = {0.f, 0.f, 0.f, 0.f};
    f32x4 acc1 = {0.f, 0.f, 0.f, 0.f};
    {
        const ushort* arow = &A[m][quad * 8];
        const ushort* wrow = Wb + (size_t)(w * 32 + m) * NFEAT + quad * 8;
#pragma unroll
        for (int k0 = 0; k0 < NFEAT; k0 += 32) {
            bf16x8 a  = *(const bf16x8*)(arow + k0);
            bf16x8 bA = *(const bf16x8*)(wrow + k0);
            bf16x8 bB = *(const bf16x8*)(wrow + 16 * NFEAT + k0);
            acc0 = __builtin_amdgcn_mfma_f32_16x16x32_bf16(a, bA, acc0, 0, 0, 0);
            acc1 = __builtin_amdgcn_mfma_f32_16x16x32_bf16(a, bB, acc1, 0, 0, 0);
        }
    }
    const float bv0 = bias[w * 32 + m];
    const float bv1 = bias[w * 32 + 16 + m];

    if (!SECOND) {
#pragma unroll
        for (int r = 0; r < 4; ++r) {
            int row = base + quad * 4 + r;
            if (row < N) {
                outB[(size_t)row * NFEAT + w * 32 + m]      = f2bf(fmaxf(acc0[r] + bv0, 0.f));
                outB[(size_t)row * NFEAT + w * 32 + 16 + m] = f2bf(fmaxf(acc1[r] + bv1, 0.f));
            }
        }
    } else {
#pragma unroll
        for (int r = 0; r < 4; ++r) {
            H2[quad * 4 + r][w * 32 + m]      = f2bf(fmaxf(acc0[r] + bv0, 0.f));
            H2[quad * 4 + r][w * 32 + 16 + m] = f2bf(fmaxf(acc1[r] + bv1, 0.f));
        }
        __syncthreads();
        // ---- phase 3: G = H2 @ W3^T, wave w -> cols [16w, 16w+16) ----
        f32x4 acc3 = {0.f, 0.f, 0.f, 0.f};
        const ushort* hrow  = &H2[m][quad * 8];
        const ushort* w3row = W3b + (size_t)(w * 16 + m) * NFEAT + quad * 8;
#pragma unroll
        for (int k0 = 0; k0 < NFEAT; k0 += 32) {
            bf16x8 a = *(const bf16x8*)(hrow + k0);
            bf16x8 b = *(const bf16x8*)(w3row + k0);
            acc3 = __builtin_amdgcn_mfma_f32_16x16x32_bf16(a, b, acc3, 0, 0, 0);
        }
#pragma unroll
        for (int r = 0; r < 4; ++r) {
            int row = base + quad * 4 + r;
            if (row < N) outB[(size_t)row * 64 + w * 16 + m] = f2bf(acc3[r]);
        }
    }
}

// ---- Final aggregation (64 feats) + bias + sigmoid (R12: 2 nodes/wave) ----

__global__ __launch_bounds__(256) void agg64_sigmoid_kernel(const ushort* __restrict__ Gb,
                                                            const int* __restrict__ row_beg,
                                                            const int* __restrict__ row_end,
                                                            const float* __restrict__ deg_inv,
                                                            const int* __restrict__ col_idx,
                                                            const float* __restrict__ bias,
                                                            float* __restrict__ out, int N) {
    const int wp   = blockIdx.x * (blockDim.x >> 6) + (threadIdx.x >> 6);
    const int lane = threadIdx.x & 63;
    const int half = lane >> 5;
    const int hl   = lane & 31;
    const int v    = wp * 2 + half;
    const bool act = (v < N);

    int beg = 0, end = 0;
    if (act) { beg = row_beg[v]; end = row_end[v]; }
    const int deg = end - beg;
    const unsigned* Gu = (const unsigned*)Gb;  // row stride 32 uints

    int cidx = 0;
    if (hl < deg) cidx = col_idx[beg + hl];

    float a0 = 0.f, a1 = 0.f, b0 = 0.f, b1 = 0.f;
    float c0 = 0.f, c1 = 0.f, d0 = 0.f, d1 = 0.f;
    const int nfast = deg < 32 ? deg : 32;
    int j = 0;
    for (; j + 3 < nfast; j += 4) {
        int s0 = __shfl(cidx, j + 0, 32);
        int s1 = __shfl(cidx, j + 1, 32);
        int s2 = __shfl(cidx, j + 2, 32);
        int s3 = __shfl(cidx, j + 3, 32);
        unsigned u0 = Gu[(size_t)s0 * 32 + hl];
        unsigned u1 = Gu[(size_t)s1 * 32 + hl];
        unsigned u2 = Gu[(size_t)s2 * 32 + hl];
        unsigned u3 = Gu[(size_t)s3 * 32 + hl];
        a0 += bflo(u0); a1 += bfhi(u0);
        b0 += bflo(u1); b1 += bfhi(u1);
        c0 += bflo(u2); c1 += bfhi(u2);
        d0 += bflo(u3); d1 += bfhi(u3);
    }
    for (; j < nfast; ++j) {
        int s0 = __shfl(cidx, j, 32);
        unsigned u0 = Gu[(size_t)s0 * 32 + hl];
        a0 += bflo(u0); a1 += bfhi(u0);
    }
    for (int e = beg + 32; e < end; ++e) {
        unsigned u0 = Gu[(size_t)col_idx[e] * 32 + hl];
        a0 += bflo(u0); a1 += bfhi(u0);
    }
    if (act) {
        unsigned us = Gu[(size_t)v * 32 + hl];
        float inv = deg_inv[v];
        float r0 = (a0 + b0 + c0 + d0 + bflo(us)) * inv + bias[hl * 2 + 0];
        float r1 = (a1 + b1 + c1 + d1 + bfhi(us)) * inv + bias[hl * 2 + 1];
        r0 = 1.0f / (1.0f + __expf(-r0));
        r1 = 1.0f / (1.0f + __expf(-r1));
        *(float2*)(out + (size_t)v * 64 + hl * 2) = make_float2(r0, r1);
    }
}

// ---------------------------------------------------------------------------

static inline size_t align256(size_t x) { return (x + 255) & ~(size_t)255; }

extern "C" void kernel_launch(void* const* d_in, const int* in_sizes, int n_in,
                              void* d_out, int out_size, void* d_ws, size_t ws_size,
                              hipStream_t stream) {
    const float* x   = (const float*)d_in[0];
    const int*   src = (const int*)d_in[1];
    const int*   dst = (const int*)d_in[2];
    const float* W1  = (const float*)d_in[3];
    const float* b1  = (const float*)d_in[4];
    const float* W2  = (const float*)d_in[5];
    const float* b2  = (const float*)d_in[6];
    const float* W3  = (const float*)d_in[7];
    const float* b3  = (const float*)d_in[8];
    float*       out = (float*)d_out;

    const int N = in_sizes[0] / NFEAT;     // 50000
    const int E = in_sizes[1];             // 800000
    const int D_OUT = in_sizes[7] / NFEAT; // 64
    const int NBUK = (N + (1 << BSH) - 1) >> BSH;   // 391
    const int SBLK = (E + EPB2 - 1) / EPB2;         // 782

    // workspace carve:
    char* ws = (char*)d_ws;
    int* row_beg      = (int*)ws;  ws += align256((size_t)N * 4);
    int* row_end      = (int*)ws;  ws += align256((size_t)N * 4);
    float* deg_inv    = (float*)ws; ws += align256((size_t)N * 4);
    int* cursor       = (int*)ws;  ws += align256((size_t)NBUK * 4);
    int* col_idx      = (int*)ws;  ws += align256((size_t)NBUK * CAP * 4);
    ushort* w1bf      = (ushort*)ws; ws += align256((size_t)NFEAT * NFEAT * 2);
    ushort* w2bf      = (ushort*)ws; ws += align256((size_t)NFEAT * NFEAT * 2);
    ushort* w3bf      = (ushort*)ws; ws += align256((size_t)D_OUT * NFEAT * 2);
    ushort* xbf       = (ushort*)ws; ws += align256((size_t)N * NFEAT * 2);
    ushort* h1bf      = (ushort*)ws; ws += align256((size_t)N * NFEAT * 2);
    ushort* gbf = xbf;                                      // x dead after fused<0>
    unsigned long long* pairs = (unsigned long long*)h1bf;  // 12.5MB <= 12.8MB, dead before fused<0>

    // ---- convert (also zeroes cursor) ----
    const int nx = N * NFEAT / 4;
    const int n1 = NFEAT * NFEAT / 4, n2 = NFEAT * NFEAT / 4, n3 = D_OUT * NFEAT / 4;
    cvt_all_kernel<<<(nx + n1 + n2 + n3 + 255) / 256, 256, 0, stream>>>(
        x, W1, W2, W3, xbf, w1bf, w2bf, w3bf, cursor, NBUK, nx, n1, n2, n3);

    // ---- CSR build: 2 passes ----
    build_scatter<<<SBLK, 256, 0, stream>>>(src, dst, cursor, pairs, E);
    build_csr<<<NBUK, 256, 0, stream>>>(pairs, cursor, row_beg, row_end, deg_inv, col_idx, N);

    const int fusedBlocks = (N + 15) / 16;   // 3125
    const int agg64Blocks = (N + 7) / 8;     // 2 nodes/wave

    // layer 1: agg(x) -> MFMA W1 + b1 + relu -> h1bf
    fused_agg_gemm_kernel<0><<<fusedBlocks, 256, 0, stream>>>(
        xbf, row_beg, row_end, deg_inv, w1bf, b1, nullptr, col_idx, h1bf, N);
    // layers 2+3a: agg(h1) -> MFMA W2 + b2 + relu -> MFMA W3 -> gbf
    fused_agg_gemm_kernel<1><<<fusedBlocks, 256, 0, stream>>>(
        h1bf, row_beg, row_end, deg_inv, w2bf, b2, w3bf, col_idx, gbf, N);
    // layer 3b: aggregate g + b3 + sigmoid -> out
    agg64_sigmoid_kernel<<<agg64Blocks, 256, 0, stream>>>(
        gbf, row_beg, row_end, deg_inv, col_idx, b3, out, N);
}